// Round 16
// baseline (238.923 us; speedup 1.0000x reference)
//
#include <hip/hip_runtime.h>
#include <hip/hip_bf16.h>
#include <math.h>

#define L_SEQ   16384
#define C_DIM   256
#define N_BATCH 4
#define N_HEAD  8
#define D_H     32
#define M_ROWS  (N_BATCH * L_SEQ)   // 65536
#define KV_SPLIT 64
#define SLAB_E  ((size_t)M_ROWS * C_DIM)   // 16,777,216 elems

typedef unsigned short u16;
typedef unsigned int   u32;
typedef short s16x8 __attribute__((ext_vector_type(8)));
typedef float f32x4 __attribute__((ext_vector_type(4)));

// ---- bf16 helpers (bit-exact bf16->f32; RNE f32->bf16) ----------------------
__device__ __forceinline__ float bf2f(u32 lo16) { return __uint_as_float(lo16 << 16); }
__device__ __forceinline__ u16 f2bf(float f) {
    u32 u = __float_as_uint(f);
    u32 rb = ((u >> 16) & 1u) + 0x7fffu;
    return (u16)((u + rb) >> 16);
}

// ---- async global->LDS, 16B per lane ---------------------------------------
__device__ __forceinline__ void gl_lds16(const u16* g, u16* l) {
    __builtin_amdgcn_global_load_lds(
        (__attribute__((address_space(1))) void*)g,
        (__attribute__((address_space(3))) void*)l, 16, 0, 0);
}

// ---------------------------------------------------------------------------
// prep_all: blocks [0,2048) = f32->bf16 convert of x (grid-stride);
// blocks [2048,2688) = weight transposes W[K][N] f32 -> Wt[rowoff+n][K] bf16.
// ---------------------------------------------------------------------------
__global__ __launch_bounds__(256)
void prep_all(const float* __restrict__ x, u16* __restrict__ xb, int n8,
              const float* __restrict__ Wq, const float* __restrict__ Wk,
              const float* __restrict__ Wv, const float* __restrict__ Wm,
              const float* __restrict__ W1, const float* __restrict__ W2,
              u16* __restrict__ wqkvt, u16* __restrict__ wmt,
              u16* __restrict__ w1t, u16* __restrict__ w2t)
{
    __shared__ float tile[32][33];
    int bt = blockIdx.x;
    if (bt < 2048) {
        int i = bt * 256 + threadIdx.x;
        int stride = 2048 * 256;
        for (; i < n8; i += stride) {
            float4 f0 = ((const float4*)x)[(size_t)i * 2];
            float4 f1 = ((const float4*)x)[(size_t)i * 2 + 1];
            uint4 o;
            o.x = (u32)f2bf(f0.x) | ((u32)f2bf(f0.y) << 16);
            o.y = (u32)f2bf(f0.z) | ((u32)f2bf(f0.w) << 16);
            o.z = (u32)f2bf(f1.x) | ((u32)f2bf(f1.y) << 16);
            o.w = (u32)f2bf(f1.z) | ((u32)f2bf(f1.w) << 16);
            ((uint4*)xb)[i] = o;
        }
        return;
    }
    bt -= 2048;
    const float* src; u16* dst; int K, N, rowoff, tt;
    if (bt < 192)      { int w = bt >> 6; tt = bt & 63;
                         src = (w == 0) ? Wq : (w == 1) ? Wk : Wv;
                         dst = wqkvt; K = 256; N = 256; rowoff = w * 256; }
    else if (bt < 256) { tt = bt - 192; src = Wm; dst = wmt; K = 256; N = 256; rowoff = 0; }
    else if (bt < 512) { tt = bt - 256; src = W1; dst = w1t; K = 512; N = 512; rowoff = 0; }
    else               { tt = bt - 512; src = W2; dst = w2t; K = 512; N = 256; rowoff = 0; }
    int ntx = N >> 5;
    int n0 = (tt % ntx) * 32, k0 = (tt / ntx) * 32;
    int tx = threadIdx.x & 31, ty = threadIdx.x >> 5;
    #pragma unroll
    for (int i = 0; i < 32; i += 8)
        tile[ty + i][tx] = src[(size_t)(k0 + ty + i) * N + n0 + tx];
    __syncthreads();
    #pragma unroll
    for (int i = 0; i < 32; i += 8)
        dst[(size_t)(rowoff + n0 + ty + i) * K + k0 + tx] = f2bf(tile[tx][ty + i]);
}

// ---------------------------------------------------------------------------
// gemm_wide: bf16 MFMA GEMM, tile 128x256, BK=32, 4 COLUMN waves, wave tile
// 128x64 (acc[8][4] -> 32 MFMA per 12 KB LDS-read per step, 1.33x better
// FLOP/LDS-byte than 64x64). True depth-1 async (2 raw barriers + vmcnt(6));
// kc-XOR swizzle; LDS-roundtrip coalesced epilogue in two 64-row halves.
// BN=256 aligns to slabs: EPI4 transform is block-uniform.
// EPI: 0=none, 3=relu, 4=qkv (slab n0>>8: 0,1 -> elu+1; 2 -> *escale).
// ---------------------------------------------------------------------------
template<int EPI>
__global__ __launch_bounds__(256)
void gemm_wide(const u16* __restrict__ A1, const u16* __restrict__ A2,
               int KA, int sA1, int sA2,
               const u16* __restrict__ Bt, int ldb,
               u16* __restrict__ C, int ldc, int K, float escale, int nx)
{
    __shared__ __align__(16) u16 smem[24576];   // 48 KB: As 2x8KB, Bs 2x16KB

    const int tid = threadIdx.x;
    const int nwg = gridDim.x;
    const int cpx = nwg >> 3;
    const int hb  = blockIdx.x;
    const int lb  = (hb & 7) * cpx + (hb >> 3);     // XCD-chunked
    const int m0 = (lb / nx) * 128;
    const int n0 = (lb % nx) * 256;
    const int wcv = tid >> 6;                       // column wave 0..3
    const int lane = tid & 63;
    const int g = lane >> 4, r = lane & 15;

    // hoisted staging addresses (swizzled k-chunk folded into base)
    const u16 *pA1[2], *pA2[2], *pB[4];
    int loffA[2], loffB[4];
    #pragma unroll
    for (int i = 0; i < 2; ++i) {
        int li  = i * 256 + tid;
        int row = li >> 2, kc = li & 3;
        int kcg = kc ^ ((row >> 1) & 3);
        pA1[i] = A1 + (size_t)(m0 + row) * sA1 + kcg * 8;
        pA2[i] = A2 + (size_t)(m0 + row) * sA2 + kcg * 8 - KA;
        loffA[i] = li * 8;
    }
    #pragma unroll
    for (int i = 0; i < 4; ++i) {
        int li  = i * 256 + tid;
        int row = li >> 2, kc = li & 3;
        int kcg = kc ^ ((row >> 1) & 3);
        pB[i] = Bt + (size_t)(n0 + row) * ldb + kcg * 8;
        loffB[i] = li * 8;
    }

    f32x4 acc[8][4] = {};

    auto stage = [&](int kt, int buf) {
        u16* As_ = smem + buf * 4096;
        u16* Bs_ = smem + 8192 + buf * 8192;
        const int ko = kt * 32;
        #pragma unroll
        for (int i = 0; i < 2; ++i) {
            const u16* Ap = ((ko < KA) ? pA1[i] : pA2[i]) + ko;
            gl_lds16(Ap, &As_[loffA[i]]);
        }
        #pragma unroll
        for (int i = 0; i < 4; ++i)
            gl_lds16(pB[i] + ko, &Bs_[loffB[i]]);
    };

    const int kts = K / 32;
    const int gsw = g ^ ((r >> 1) & 3);             // swizzled k-chunk slot
    stage(0, 0);
    for (int kt = 0; kt < kts; ++kt) {
        const int cur = kt & 1;
        asm volatile("s_barrier" ::: "memory");     // A: buf^1 readers done
        if (kt + 1 < kts) {
            stage(kt + 1, cur ^ 1);
            asm volatile("s_waitcnt vmcnt(6)" ::: "memory");  // stage(kt) landed
        } else {
            asm volatile("s_waitcnt vmcnt(0)" ::: "memory");
        }
        asm volatile("s_barrier" ::: "memory");     // B: all stage(kt) done

        const u16* Ar = smem + cur * 4096;
        const u16* Br = smem + 8192 + cur * 8192;
        s16x8 b[4];
        #pragma unroll
        for (int ni = 0; ni < 4; ++ni)
            b[ni] = *(const s16x8*)&Br[(wcv * 64 + ni * 16 + r) * 32 + gsw * 8];
        __builtin_amdgcn_s_setprio(1);
        #pragma unroll
        for (int mi = 0; mi < 8; ++mi) {
            s16x8 av = *(const s16x8*)&Ar[(mi * 16 + r) * 32 + gsw * 8];
            // swapped operands -> C^T frag: reg j = col (ni*16+g*4+j), row mi*16+r
            #pragma unroll
            for (int ni = 0; ni < 4; ++ni)
                asm volatile("v_mfma_f32_16x16x32_bf16 %0, %1, %2, %0"
                             : "+v"(acc[mi][ni]) : "v"(b[ni]), "v"(av));
        }
        __builtin_amdgcn_s_setprio(0);
    }

    asm volatile("s_nop 7");
    asm volatile("s_nop 7");

    // ---- LDS-roundtrip epilogue: two halves of 64 rows (32 KB each) ----
    const bool vslab = (EPI == 4) && (n0 >= 512);
    u16* outp;
    if (EPI == 4) outp = C + (size_t)(n0 >> 8) * SLAB_E;   // slab base, 256-wide
    else          outp = C + n0;
    char* ct = (char*)smem;
    #pragma unroll
    for (int hh = 0; hh < 2; ++hh) {
        __syncthreads();
        #pragma unroll
        for (int mi2 = 0; mi2 < 4; ++mi2) {
            int mi = hh * 4 + mi2;
            int rl = mi2 * 16 + r;                  // row within half
            #pragma unroll
            for (int ni = 0; ni < 4; ++ni) {
                int cl = wcv * 64 + ni * 16 + g * 4;
                ushort4 o;
                #pragma unroll
                for (int j = 0; j < 4; ++j) {
                    float v = acc[mi][ni][j];
                    if (EPI == 3)      v = (v > 0.f) ? v : 0.f;
                    else if (EPI == 4) v = vslab ? v * escale
                                                 : ((v > 0.f) ? (v + 1.f) : __expf(v));
                    (&o.x)[j] = f2bf(v);
                }
                int byte = (rl * 512 + cl * 2) ^ ((rl & 7) << 4);
                *(ushort4*)(ct + byte) = o;
            }
        }
        __syncthreads();
        const int rr = tid >> 5, ck = tid & 31;     // 8 rows x 32 chunks/pass
        #pragma unroll
        for (int it = 0; it < 8; ++it) {
            int rl = it * 8 + rr;
            int byte = (rl * 512 + ck * 16) ^ ((rl & 7) << 4);
            uint4 val = *(const uint4*)(ct + byte);
            size_t row = (size_t)(m0 + hh * 64 + rl);
            if (EPI == 4)
                *(uint4*)(outp + row * 256 + ck * 8) = val;
            else
                *(uint4*)(outp + row * (size_t)ldc + ck * 8) = val;
        }
    }
}

// ---------------------------------------------------------------------------
// gemm128: bf16 MFMA GEMM, tile 128x128 (R13-exact). Used for the tiny
// bdwt GEMM. True depth-1 async; kc-XOR swizzle; LDS-roundtrip epilogue.
// EPI: 0=none.
// ---------------------------------------------------------------------------
template<int EPI>
__global__ __launch_bounds__(256)
void gemm128(const u16* __restrict__ A1, const u16* __restrict__ A2,
             int KA, int sA1, int sA2,
             const u16* __restrict__ Bt, int ldb, int bstride,
             u16* __restrict__ C, int ldc, int K, float escale, int nx)
{
    __shared__ __align__(16) u16 smem[16384];   // 32 KB

    const int tid = threadIdx.x;
    const int nwg = gridDim.x;
    const int cpx = nwg >> 3;
    const int hb  = blockIdx.x;
    const int lb  = (hb & 7) * cpx + (hb >> 3);
    const int m0 = (lb / nx) * 128;
    const int n0 = (lb % nx) * 128;
    const int w = tid >> 6, lane = tid & 63;
    const int wr = w >> 1, wc = w & 1;
    const int g = lane >> 4, r = lane & 15;

    Bt += (size_t)(m0 / L_SEQ) * bstride;

    const u16 *pA1[2], *pA2[2], *pB[2];
    int loff[2];
    #pragma unroll
    for (int i = 0; i < 2; ++i) {
        int li  = i * 256 + tid;
        int row = li >> 2, kc = li & 3;
        int kcg = kc ^ ((row >> 1) & 3);
        pA1[i] = A1 + (size_t)(m0 + row) * sA1 + kcg * 8;
        pA2[i] = A2 + (size_t)(m0 + row) * sA2 + kcg * 8 - KA;
        pB[i]  = Bt + (size_t)(n0 + row) * ldb + kcg * 8;
        loff[i] = li * 8;
    }

    f32x4 acc[4][4] = {};

    auto stage = [&](int kt, int buf) {
        u16* As_ = smem + buf * 4096;
        u16* Bs_ = smem + 8192 + buf * 4096;
        const int ko = kt * 32;
        #pragma unroll
        for (int i = 0; i < 2; ++i) {
            const u16* Ap = ((ko < KA) ? pA1[i] : pA2[i]) + ko;
            gl_lds16(Ap, &As_[loff[i]]);
            gl_lds16(pB[i] + ko, &Bs_[loff[i]]);
        }
    };

    const int kts = K / 32;
    const int gsw = g ^ ((r >> 1) & 3);
    stage(0, 0);
    for (int kt = 0; kt < kts; ++kt) {
        const int cur = kt & 1;
        asm volatile("s_barrier" ::: "memory");
        if (kt + 1 < kts) {
            stage(kt + 1, cur ^ 1);
            asm volatile("s_waitcnt vmcnt(4)" ::: "memory");
        } else {
            asm volatile("s_waitcnt vmcnt(0)" ::: "memory");
        }
        asm volatile("s_barrier" ::: "memory");

        const u16* Ar = smem + cur * 4096;
        const u16* Br = smem + 8192 + cur * 4096;
        s16x8 a[4], b[4];
        #pragma unroll
        for (int mi = 0; mi < 4; ++mi)
            a[mi] = *(const s16x8*)&Ar[(wr * 64 + mi * 16 + r) * 32 + gsw * 8];
        #pragma unroll
        for (int ni = 0; ni < 4; ++ni)
            b[ni] = *(const s16x8*)&Br[(wc * 64 + ni * 16 + r) * 32 + gsw * 8];
        __builtin_amdgcn_s_setprio(1);
        #pragma unroll
        for (int mi = 0; mi < 4; ++mi)
            #pragma unroll
            for (int ni = 0; ni < 4; ++ni)
                asm volatile("v_mfma_f32_16x16x32_bf16 %0, %1, %2, %0"
                             : "+v"(acc[mi][ni]) : "v"(b[ni]), "v"(a[mi]));
        __builtin_amdgcn_s_setprio(0);
    }

    asm volatile("s_nop 7");
    asm volatile("s_nop 7");

    __syncthreads();
    char* ct = (char*)smem;
    #pragma unroll
    for (int mi = 0; mi < 4; ++mi) {
        int rl = wr * 64 + mi * 16 + r;
        #pragma unroll
        for (int ni = 0; ni < 4; ++ni) {
            int cl = wc * 64 + ni * 16 + g * 4;
            ushort4 o;
            #pragma unroll
            for (int j = 0; j < 4; ++j)
                (&o.x)[j] = f2bf(acc[mi][ni][j]);
            int byte = (rl * 256 + cl * 2) ^ ((rl & 7) << 4);
            *(ushort4*)(ct + byte) = o;
        }
    }
    __syncthreads();
    {
        const int rr = tid >> 4, ck = tid & 15;
        #pragma unroll
        for (int it = 0; it < 8; ++it) {
            int rl = it * 16 + rr;
            int byte = (rl * 256 + ck * 16) ^ ((rl & 7) << 4);
            uint4 val = *(const uint4*)(ct + byte);
            size_t row = (size_t)(m0 + rl);
            *(uint4*)(C + row * (size_t)ldc + n0 + ck * 8) = val;
        }
    }
}

// ---------------------------------------------------------------------------
// gemm_ln: 128x256-tile GEMM + fused LayerNorm epilogue, LDS-roundtrip
// coalesced stores, hoisted staging. EPI: 5=LN->bf16 C; 6=LN+xres->f32 outf.
// ---------------------------------------------------------------------------
template<int EPI>
__global__ __launch_bounds__(256)
void gemm_ln(const u16* __restrict__ A1, const u16* __restrict__ A2,
             int KA, int sA1, int sA2,
             const u16* __restrict__ Bt, int ldb, int bstride,
             u16* __restrict__ C, int ldc, int K, float escale, int nx,
             const float* __restrict__ gw, const float* __restrict__ bw,
             const float* __restrict__ xres, float* __restrict__ outf)
{
    __shared__ __align__(16) u16 smem[24576];       // 48 KB
    __shared__ float red[4][2][128];                // 4 KB (LN reduce)

    const int tid = threadIdx.x;
    const int nwg = gridDim.x;
    const int cpx = nwg >> 3;
    const int hb  = blockIdx.x;
    const int lb  = (hb & 7) * cpx + (hb >> 3);
    const int m0 = (lb / nx) * 128;
    const int n0 = (lb % nx) * 256;
    const int wc = tid >> 6;
    const int lane = tid & 63;
    const int g = lane >> 4, r = lane & 15;

    const u16* Btb = Bt + (size_t)(m0 / L_SEQ) * bstride;

    const u16 *pA1[2], *pA2[2], *pB[4];
    int loffA[2], loffB[4];
    #pragma unroll
    for (int i = 0; i < 2; ++i) {
        int li  = i * 256 + tid;
        int row = li >> 2, kc = li & 3;
        int kcg = kc ^ ((row >> 1) & 3);
        pA1[i] = A1 + (size_t)(m0 + row) * sA1 + kcg * 8;
        pA2[i] = A2 + (size_t)(m0 + row) * sA2 + kcg * 8 - KA;
        loffA[i] = li * 8;
    }
    #pragma unroll
    for (int i = 0; i < 4; ++i) {
        int li  = i * 256 + tid;
        int row = li >> 2, kc = li & 3;
        int kcg = kc ^ ((row >> 1) & 3);
        pB[i] = Btb + (size_t)(n0 + row) * ldb + kcg * 8;
        loffB[i] = li * 8;
    }

    f32x4 acc[8][4] = {};

    auto stage = [&](int kt, int buf) {
        u16* As_ = smem + buf * 4096;
        u16* Bs_ = smem + 8192 + buf * 8192;
        const int ko = kt * 32;
        #pragma unroll
        for (int i = 0; i < 2; ++i) {
            const u16* Ap = ((ko < KA) ? pA1[i] : pA2[i]) + ko;
            gl_lds16(Ap, &As_[loffA[i]]);
        }
        #pragma unroll
        for (int i = 0; i < 4; ++i)
            gl_lds16(pB[i] + ko, &Bs_[loffB[i]]);
    };

    const int kts = K / 32;
    const int gsw = g ^ ((r >> 1) & 3);
    stage(0, 0);
    for (int kt = 0; kt < kts; ++kt) {
        const int cur = kt & 1;
        asm volatile("s_barrier" ::: "memory");
        if (kt + 1 < kts) {
            stage(kt + 1, cur ^ 1);
            asm volatile("s_waitcnt vmcnt(6)" ::: "memory");
        } else {
            asm volatile("s_waitcnt vmcnt(0)" ::: "memory");
        }
        asm volatile("s_barrier" ::: "memory");

        const u16* Ar = smem + cur * 4096;
        const u16* Br = smem + 8192 + cur * 8192;
        s16x8 b[4];
        #pragma unroll
        for (int ni = 0; ni < 4; ++ni)
            b[ni] = *(const s16x8*)&Br[(wc * 64 + ni * 16 + r) * 32 + gsw * 8];
        __builtin_amdgcn_s_setprio(1);
        #pragma unroll
        for (int mi = 0; mi < 8; ++mi) {
            s16x8 av = *(const s16x8*)&Ar[(mi * 16 + r) * 32 + gsw * 8];
            #pragma unroll
            for (int ni = 0; ni < 4; ++ni)
                asm volatile("v_mfma_f32_16x16x32_bf16 %0, %1, %2, %0"
                             : "+v"(acc[mi][ni]) : "v"(b[ni]), "v"(av));
        }
        __builtin_amdgcn_s_setprio(0);
    }

    asm volatile("s_nop 7");
    asm volatile("s_nop 7");

    // ---- LN stats (full rows in-block) ----
    #pragma unroll
    for (int mi = 0; mi < 8; ++mi) {
        float s = 0.f, s2 = 0.f;
        #pragma unroll
        for (int ni = 0; ni < 4; ++ni)
            #pragma unroll
            for (int j = 0; j < 4; ++j) {
                float v = acc[mi][ni][j];
                s += v; s2 += v * v;
            }
        s  += __shfl_xor(s, 16);  s  += __shfl_xor(s, 32);
        s2 += __shfl_xor(s2, 16); s2 += __shfl_xor(s2, 32);
        if (g == 0) {
            red[wc][0][mi * 16 + r] = s;
            red[wc][1][mi * 16 + r] = s2;
        }
    }
    __syncthreads();

    float4 gv[4], bv[4];
    #pragma unroll
    for (int ni = 0; ni < 4; ++ni) {
        int c = wc * 64 + ni * 16 + g * 4;
        gv[ni] = *(const float4*)&gw[c];
        bv[ni] = *(const float4*)&bw[c];
    }

    char* ct = (char*)smem;
    if (EPI == 5) {
        #pragma unroll
        for (int h = 0; h < 2; ++h) {
            __syncthreads();
            #pragma unroll
            for (int mi2 = 0; mi2 < 4; ++mi2) {
                int mi = h * 4 + mi2;
                int rlg = mi * 16 + r;
                int rl = rlg - h * 64;
                float S  = red[0][0][rlg] + red[1][0][rlg] + red[2][0][rlg] + red[3][0][rlg];
                float S2 = red[0][1][rlg] + red[1][1][rlg] + red[2][1][rlg] + red[3][1][rlg];
                float mu = S * (1.0f / 256.0f);
                float var = S2 * (1.0f / 256.0f) - mu * mu;
                float rstd = rsqrtf(var + 1e-5f);
                #pragma unroll
                for (int ni = 0; ni < 4; ++ni) {
                    int cl = wc * 64 + ni * 16 + g * 4;
                    ushort4 o;
                    o.x = f2bf((acc[mi][ni][0] - mu) * rstd * gv[ni].x + bv[ni].x);
                    o.y = f2bf((acc[mi][ni][1] - mu) * rstd * gv[ni].y + bv[ni].y);
                    o.z = f2bf((acc[mi][ni][2] - mu) * rstd * gv[ni].z + bv[ni].z);
                    o.w = f2bf((acc[mi][ni][3] - mu) * rstd * gv[ni].w + bv[ni].w);
                    int byte = (rl * 512 + cl * 2) ^ ((rl & 7) << 4);
                    *(ushort4*)(ct + byte) = o;
                }
            }
            __syncthreads();
            const int rr = tid >> 5, ck = tid & 31;
            #pragma unroll
            for (int it = 0; it < 8; ++it) {
                int rl = it * 8 + rr;
                int byte = (rl * 512 + ck * 16) ^ ((rl & 7) << 4);
                uint4 val = *(const uint4*)(ct + byte);
                size_t row = (size_t)(m0 + h * 64 + rl);
                *(uint4*)(C + row * 256 + ck * 8) = val;
            }
        }
    } else {
        #pragma unroll
        for (int qd = 0; qd < 4; ++qd) {
            __syncthreads();
            #pragma unroll
            for (int mi2 = 0; mi2 < 2; ++mi2) {
                int mi = qd * 2 + mi2;
                int rlg = mi * 16 + r;
                int rl = rlg - qd * 32;
                float S  = red[0][0][rlg] + red[1][0][rlg] + red[2][0][rlg] + red[3][0][rlg];
                float S2 = red[0][1][rlg] + red[1][1][rlg] + red[2][1][rlg] + red[3][1][rlg];
                float mu = S * (1.0f / 256.0f);
                float var = S2 * (1.0f / 256.0f) - mu * mu;
                float rstd = rsqrtf(var + 1e-5f);
                #pragma unroll
                for (int ni = 0; ni < 4; ++ni) {
                    int cl = wc * 64 + ni * 16 + g * 4;
                    float4 o;
                    o.x = (acc[mi][ni][0] - mu) * rstd * gv[ni].x + bv[ni].x;
                    o.y = (acc[mi][ni][1] - mu) * rstd * gv[ni].y + bv[ni].y;
                    o.z = (acc[mi][ni][2] - mu) * rstd * gv[ni].z + bv[ni].z;
                    o.w = (acc[mi][ni][3] - mu) * rstd * gv[ni].w + bv[ni].w;
                    int byte = (rl * 1024 + cl * 4) ^ ((rl & 7) << 4);
                    *(float4*)(ct + byte) = o;
                }
            }
            __syncthreads();
            const int rr = tid >> 6, ck = tid & 63;
            #pragma unroll
            for (int it = 0; it < 8; ++it) {
                int rl = it * 4 + rr;
                int byte = (rl * 1024 + ck * 16) ^ ((rl & 7) << 4);
                float4 val = *(const float4*)(ct + byte);
                size_t row = (size_t)(m0 + qd * 32 + rl);
                float4 xv = *(const float4*)&xres[row * 256 + ck * 4];
                val.x += xv.x; val.y += xv.y; val.z += xv.z; val.w += xv.w;
                *(float4*)&outf[row * 256 + ck * 4] = val;
            }
        }
    }
}

// ---------------------------------------------------------------------------
// KV partial over L-chunks: KV[32][32] += K^T v ; Ksum[32] += K. f32 accum.
// ---------------------------------------------------------------------------
__global__ __launch_bounds__(256)
void kv_partial(const u16* __restrict__ Kf, const u16* __restrict__ Vf, int ld,
                float* __restrict__ part)
{
    int b  = blockIdx.x;
    int s  = b & (KV_SPLIT - 1);
    int nh = b / KV_SPLIT;
    int h  = nh & (N_HEAD - 1);
    int n  = nh / N_HEAD;
    int t  = threadIdx.x;

    __shared__ __align__(16) float Ks[32][D_H];
    __shared__ __align__(16) float Vs[32][D_H];

    const int d   = t >> 3;
    const int dv0 = (t & 7) * 4;
    const int lr  = t >> 3;
    const int lc  = (t & 7) * 4;
    const size_t base = ((size_t)n * L_SEQ) * ld + h * D_H;

    float a0 = 0, a1 = 0, a2 = 0, a3 = 0, asum = 0;
    const int CH = L_SEQ / KV_SPLIT;
    for (int l = s * CH; l < s * CH + CH; l += 32) {
        __syncthreads();
        uint2 ku = *(const uint2*)&Kf[base + (size_t)(l + lr) * ld + lc];
        uint2 vu = *(const uint2*)&Vf[base + (size_t)(l + lr) * ld + lc];
        Ks[lr][lc] = bf2f(ku.x & 0xffff); Ks[lr][lc + 1] = bf2f(ku.x >> 16);
        Ks[lr][lc + 2] = bf2f(ku.y & 0xffff); Ks[lr][lc + 3] = bf2f(ku.y >> 16);
        Vs[lr][lc] = bf2f(vu.x & 0xffff); Vs[lr][lc + 1] = bf2f(vu.x >> 16);
        Vs[lr][lc + 2] = bf2f(vu.y & 0xffff); Vs[lr][lc + 3] = bf2f(vu.y >> 16);
        __syncthreads();
        #pragma unroll
        for (int i = 0; i < 32; ++i) {
            float kv = Ks[i][d];
            float4 vv = *(const float4*)&Vs[i][dv0];
            a0 = fmaf(kv, vv.x, a0);
            a1 = fmaf(kv, vv.y, a1);
            a2 = fmaf(kv, vv.z, a2);
            a3 = fmaf(kv, vv.w, a3);
            asum += kv;
        }
    }
    float* p = part + (size_t)b * 1056;
    p[d * D_H + dv0 + 0] = a0;
    p[d * D_H + dv0 + 1] = a1;
    p[d * D_H + dv0 + 2] = a2;
    p[d * D_H + dv0 + 3] = a3;
    if ((t & 7) == 0) p[1024 + d] = asum;
}

// ---------------------------------------------------------------------------
// kv_final + bdr build fused: reduces partials, writes Ksum + block-diagonal
// bdr rows. bdr row (h*32+rr), col j within head block = KVs[rr][j].
// ---------------------------------------------------------------------------
__global__ __launch_bounds__(256)
void kv_final(const float* __restrict__ part, float* __restrict__ Ksum,
              u16* __restrict__ bdr)
{
    __shared__ float KVs[D_H][D_H];   // [d][dv]
    int nh = blockIdx.x;
    int h  = nh & (N_HEAD - 1);
    int n  = nh / N_HEAD;
    int t  = threadIdx.x;

    float ax = 0, ay = 0, az = 0, aw = 0, ssum = 0;
    const float* p0 = part + (size_t)nh * KV_SPLIT * 1056;
    for (int s = 0; s < KV_SPLIT; ++s) {
        const float* p = p0 + (size_t)s * 1056;
        float4 v = *(const float4*)&p[t * 4];
        ax += v.x; ay += v.y; az += v.z; aw += v.w;
        if (t < D_H) ssum += p[1024 + t];
    }
    const int d = t >> 3, dv0 = (t & 7) * 4;
    KVs[d][dv0] = ax; KVs[d][dv0 + 1] = ay; KVs[d][dv0 + 2] = az; KVs[d][dv0 + 3] = aw;
    if (t < D_H) Ksum[nh * D_H + t] = ssum;
    __syncthreads();

    const int rr = t >> 3;
    const int c0 = (t & 7) * 32;
    u16* dst = bdr + ((size_t)n * 256 + h * 32 + rr) * 256 + c0;
    if (c0 == h * 32) {
        #pragma unroll
        for (int j = 0; j < 32; j += 4) {
            float4 vv = *(const float4*)&KVs[rr][j];
            ushort4 o;
            o.x = f2bf(vv.x); o.y = f2bf(vv.y); o.z = f2bf(vv.z); o.w = f2bf(vv.w);
            *(ushort4*)(dst + j) = o;
        }
    } else {
        uint4 z = make_uint4(0, 0, 0, 0);
        #pragma unroll
        for (int j = 0; j < 32; j += 8)
            *(uint4*)(dst + j) = z;
    }
}

// ---------------------------------------------------------------------------
// attn_z: q[tok][c] *= L / (q[tok] . Ksum_head(c) + eps), in place. (R13)
// ---------------------------------------------------------------------------
#define NT_TOK 32
__global__ __launch_bounds__(256)
void attn_z(u16* __restrict__ q, const float* __restrict__ Ksum)
{
    const int t = threadIdx.x;
    const int w = t >> 6, lane = t & 63;
    const int tok0 = blockIdx.x * NT_TOK;
    const int n = tok0 / L_SEQ;
    float4 ks = *(const float4*)&Ksum[n * C_DIM + lane * 4];

    for (int i = 0; i < NT_TOK; i += 4) {
        int tok = tok0 + i + w;
        u16* qp = q + (size_t)tok * C_DIM + lane * 4;
        uint2 qu = *(const uint2*)qp;
        float q0 = bf2f(qu.x & 0xffff), q1 = bf2f(qu.x >> 16);
        float q2 = bf2f(qu.y & 0xffff), q3 = bf2f(qu.y >> 16);
        float p = q0 * ks.x + q1 * ks.y + q2 * ks.z + q3 * ks.w;
        p += __shfl_xor(p, 1);
        p += __shfl_xor(p, 2);
        p += __shfl_xor(p, 4);
        float z = (float)L_SEQ / (p + 1e-6f);
        uint2 o;
        o.x = (u32)f2bf(q0 * z) | ((u32)f2bf(q1 * z) << 16);
        o.y = (u32)f2bf(q2 * z) | ((u32)f2bf(q3 * z) << 16);
        *(uint2*)qp = o;
    }
}

// ---------------------------------------------------------------------------
extern "C" void kernel_launch(void* const* d_in, const int* in_sizes, int n_in,
                              void* d_out, int out_size, void* d_ws, size_t ws_size,
                              hipStream_t stream)
{
    const float* x  = (const float*)d_in[0];
    const float* Wq = (const float*)d_in[1];
    const float* Wk = (const float*)d_in[2];
    const float* Wv = (const float*)d_in[3];
    const float* Wm = (const float*)d_in[4];
    const float* W1 = (const float*)d_in[5];
    const float* W2 = (const float*)d_in[6];
    const float* g1 = (const float*)d_in[7];
    const float* b1 = (const float*)d_in[8];
    const float* g2 = (const float*)d_in[9];
    const float* b2 = (const float*)d_in[10];
    float* out = (float*)d_out;

    u16* xb  = (u16*)d_ws;          // slab 0
    u16* q   = xb + SLAB_E;         // slab 1  (q' after attn_z; h-lo after)
    u16* k   = q + SLAB_E;          // slab 2  (dead after kv -> h-hi)
    u16* v   = k + SLAB_E;          // slab 3  (dead after kv)
    u16* ln1 = v + SLAB_E;          // slab 4
    u16* h   = q;                   // spans q..k (M x 512), q'/k dead by then
    // weights (transposed bf16) + small buffers
    u16* wqkvt = ln1 + SLAB_E;             // 768*256
    u16* wmt   = wqkvt + 768 * 256;        // 256*256
    u16* w1t   = wmt + 256 * 256;          // 512*512
    u16* w2t   = w1t + 512 * 512;          // 256*512
    u16* bdr   = w2t + 256 * 512;          // 4*256*256
    u16* bdwt  = bdr + (size_t)N_BATCH * 256 * 256;   // 4*256*256, [c][b*256+k]
    float* Ksum = (float*)(bdwt + (size_t)N_BATCH * 256 * 256);
    float* part = Ksum + (size_t)N_BATCH * N_HEAD * D_H;

    dim3 blk(256);
    const float invL = 1.0f / (float)L_SEQ;

    // ---- prep (convert + all weight transposes, one launch) ----
    prep_all<<<2688, blk, 0, stream>>>(x, xb, (int)(SLAB_E / 8),
                                       Wq, Wk, Wv, Wm, W1, W2,
                                       wqkvt, wmt, w1t, w2t);

    // ---- fused QKV projection -> dense q,k,v slabs (128x256 tiles, nx=3) ----
    gemm_wide<4><<<(M_ROWS / 128) * 3, blk, 0, stream>>>(
        xb, xb, 256, 256, 256, wqkvt, 256, q, 256, 256, invL, 3);

    // ---- KV reduction (+ fused bdr build) ----
    kv_partial<<<N_BATCH * N_HEAD * KV_SPLIT, blk, 0, stream>>>(k, v, 256, part);
    kv_final<<<N_BATCH * N_HEAD, blk, 0, stream>>>(part, Ksum, bdr);

    // ---- BDW = BD @ Wm (tiny GEMM), bdwt[c][b*256+k] ----
    gemm128<0><<<16, blk, 0, stream>>>(
        wmt, wmt, 256, 256, 256, bdr, 256, 0, bdwt, 1024, 256, 1.f, 8);

    // ---- q' = q * z (in place) ----
    attn_z<<<M_ROWS / NT_TOK, blk, 0, stream>>>(q, Ksum);

    // ---- ln1 = LN(q' @ BDW_b; g1,b1)  (fused epilogue) ----
    gemm_ln<5><<<M_ROWS / 128, blk, 0, stream>>>(
        q, q, 256, 256, 256, bdwt, 1024, 256, ln1, 256, 256, 1.f, 1,
        g1, b1, nullptr, nullptr);

    // ---- h = relu(concat(xb, ln1) @ W1)  (128x256 tiles, nx=2) ----
    gemm_wide<3><<<(M_ROWS / 128) * 2, blk, 0, stream>>>(
        xb, ln1, 256, 256, 256, w1t, 512, h, 512, 512, 1.f, 2);

    // ---- out = x + LN(h @ W2; g2,b2)  (fused epilogue, f32 out) ----
    gemm_ln<6><<<M_ROWS / 128, blk, 0, stream>>>(
        h, h, 512, 512, 512, w2t, 512, 0, nullptr, 256, 512, 1.f, 1,
        g2, b2, x, out);
}

// Round 17
// 231.677 us; speedup vs baseline: 1.0313x; 1.0313x over previous
//
#include <hip/hip_runtime.h>
#include <hip/hip_bf16.h>
#include <math.h>

#define L_SEQ   16384
#define C_DIM   256
#define N_BATCH 4
#define N_HEAD  8
#define D_H     32
#define M_ROWS  (N_BATCH * L_SEQ)   // 65536
#define KV_SPLIT 64
#define SLAB_E  ((size_t)M_ROWS * C_DIM)   // 16,777,216 elems

typedef unsigned short u16;
typedef unsigned int   u32;
typedef short s16x8 __attribute__((ext_vector_type(8)));
typedef float f32x4 __attribute__((ext_vector_type(4)));

// ---- bf16 helpers (bit-exact bf16->f32; RNE f32->bf16) ----------------------
__device__ __forceinline__ float bf2f(u32 lo16) { return __uint_as_float(lo16 << 16); }
__device__ __forceinline__ u16 f2bf(float f) {
    u32 u = __float_as_uint(f);
    u32 rb = ((u >> 16) & 1u) + 0x7fffu;
    return (u16)((u + rb) >> 16);
}

// ---- async global->LDS, 16B per lane ---------------------------------------
__device__ __forceinline__ void gl_lds16(const u16* g, u16* l) {
    __builtin_amdgcn_global_load_lds(
        (__attribute__((address_space(1))) void*)g,
        (__attribute__((address_space(3))) void*)l, 16, 0, 0);
}

// ---------------------------------------------------------------------------
// prep_all: blocks [0,2048) = f32->bf16 convert of x (grid-stride);
// blocks [2048,2688) = weight transposes W[K][N] f32 -> Wt[rowoff+n][K] bf16.
// ---------------------------------------------------------------------------
__global__ __launch_bounds__(256)
void prep_all(const float* __restrict__ x, u16* __restrict__ xb, int n8,
              const float* __restrict__ Wq, const float* __restrict__ Wk,
              const float* __restrict__ Wv, const float* __restrict__ Wm,
              const float* __restrict__ W1, const float* __restrict__ W2,
              u16* __restrict__ wqkvt, u16* __restrict__ wmt,
              u16* __restrict__ w1t, u16* __restrict__ w2t)
{
    __shared__ float tile[32][33];
    int bt = blockIdx.x;
    if (bt < 2048) {
        int i = bt * 256 + threadIdx.x;
        int stride = 2048 * 256;
        for (; i < n8; i += stride) {
            float4 f0 = ((const float4*)x)[(size_t)i * 2];
            float4 f1 = ((const float4*)x)[(size_t)i * 2 + 1];
            uint4 o;
            o.x = (u32)f2bf(f0.x) | ((u32)f2bf(f0.y) << 16);
            o.y = (u32)f2bf(f0.z) | ((u32)f2bf(f0.w) << 16);
            o.z = (u32)f2bf(f1.x) | ((u32)f2bf(f1.y) << 16);
            o.w = (u32)f2bf(f1.z) | ((u32)f2bf(f1.w) << 16);
            ((uint4*)xb)[i] = o;
        }
        return;
    }
    bt -= 2048;
    const float* src; u16* dst; int K, N, rowoff, tt;
    if (bt < 192)      { int w = bt >> 6; tt = bt & 63;
                         src = (w == 0) ? Wq : (w == 1) ? Wk : Wv;
                         dst = wqkvt; K = 256; N = 256; rowoff = w * 256; }
    else if (bt < 256) { tt = bt - 192; src = Wm; dst = wmt; K = 256; N = 256; rowoff = 0; }
    else if (bt < 512) { tt = bt - 256; src = W1; dst = w1t; K = 512; N = 512; rowoff = 0; }
    else               { tt = bt - 512; src = W2; dst = w2t; K = 512; N = 256; rowoff = 0; }
    int ntx = N >> 5;
    int n0 = (tt % ntx) * 32, k0 = (tt / ntx) * 32;
    int tx = threadIdx.x & 31, ty = threadIdx.x >> 5;
    #pragma unroll
    for (int i = 0; i < 32; i += 8)
        tile[ty + i][tx] = src[(size_t)(k0 + ty + i) * N + n0 + tx];
    __syncthreads();
    #pragma unroll
    for (int i = 0; i < 32; i += 8)
        dst[(size_t)(rowoff + n0 + ty + i) * K + k0 + tx] = f2bf(tile[tx][ty + i]);
}

// ---------------------------------------------------------------------------
// gemm128: bf16 MFMA GEMM, tile 128x128, BK=32, 4 waves (2x2), acc[4][4].
// True depth-1 async (2 raw barriers + counted vmcnt(4)); kc-XOR LDS swizzle;
// LDS-roundtrip coalesced epilogue; hoisted staging addresses. (R13-exact:
// wider tiles / deeper rings all regress via occupancy loss.)
// EPI: 0=none, 3=relu, 4=qkv split (q/k/v slabs, ldc fixed 256).
// ---------------------------------------------------------------------------
template<int EPI>
__global__ __launch_bounds__(256)
void gemm128(const u16* __restrict__ A1, const u16* __restrict__ A2,
             int KA, int sA1, int sA2,
             const u16* __restrict__ Bt, int ldb, int bstride,
             u16* __restrict__ C, int ldc, int K, float escale, int nx)
{
    __shared__ __align__(16) u16 smem[16384];   // 32 KB: As0,As1,Bs0,Bs1 / C-tile

    const int tid = threadIdx.x;
    const int nwg = gridDim.x;
    const int cpx = nwg >> 3;
    const int hb  = blockIdx.x;
    const int lb  = (hb & 7) * cpx + (hb >> 3);     // XCD-chunked
    const int m0 = (lb / nx) * 128;
    const int n0 = (lb % nx) * 128;
    const int w = tid >> 6, lane = tid & 63;
    const int wr = w >> 1, wc = w & 1;
    const int g = lane >> 4, r = lane & 15;

    Bt += (size_t)(m0 / L_SEQ) * bstride;

    // hoisted per-thread staging addresses (swizzled col folded into base)
    const u16 *pA1[2], *pA2[2], *pB[2];
    int loff[2];
    #pragma unroll
    for (int i = 0; i < 2; ++i) {
        int li  = i * 256 + tid;
        int row = li >> 2, kc = li & 3;
        int kcg = kc ^ ((row >> 1) & 3);
        pA1[i] = A1 + (size_t)(m0 + row) * sA1 + kcg * 8;
        pA2[i] = A2 + (size_t)(m0 + row) * sA2 + kcg * 8 - KA;
        pB[i]  = Bt + (size_t)(n0 + row) * ldb + kcg * 8;
        loff[i] = li * 8;
    }

    f32x4 acc[4][4] = {};

    auto stage = [&](int kt, int buf) {
        u16* As_ = smem + buf * 4096;
        u16* Bs_ = smem + 8192 + buf * 4096;
        const int ko = kt * 32;
        #pragma unroll
        for (int i = 0; i < 2; ++i) {
            const u16* Ap = ((ko < KA) ? pA1[i] : pA2[i]) + ko;
            gl_lds16(Ap, &As_[loff[i]]);
            gl_lds16(pB[i] + ko, &Bs_[loff[i]]);
        }
    };

    const int kts = K / 32;
    const int gsw = g ^ ((r >> 1) & 3);             // swizzled k-chunk slot
    stage(0, 0);
    for (int kt = 0; kt < kts; ++kt) {
        const int cur = kt & 1;
        asm volatile("s_barrier" ::: "memory");     // A: buf^1 readers done
        if (kt + 1 < kts) {
            stage(kt + 1, cur ^ 1);
            asm volatile("s_waitcnt vmcnt(4)" ::: "memory");  // stage(kt) landed
        } else {
            asm volatile("s_waitcnt vmcnt(0)" ::: "memory");
        }
        asm volatile("s_barrier" ::: "memory");     // B: all waves' stage(kt) done

        const u16* Ar = smem + cur * 4096;
        const u16* Br = smem + 8192 + cur * 4096;
        s16x8 a[4], b[4];
        #pragma unroll
        for (int mi = 0; mi < 4; ++mi)
            a[mi] = *(const s16x8*)&Ar[(wr * 64 + mi * 16 + r) * 32 + gsw * 8];
        #pragma unroll
        for (int ni = 0; ni < 4; ++ni)
            b[ni] = *(const s16x8*)&Br[(wc * 64 + ni * 16 + r) * 32 + gsw * 8];
        __builtin_amdgcn_s_setprio(1);
        // swapped operands -> C^T frags: reg j = col (ni*16+g*4+j), row mi*16+r
        #pragma unroll
        for (int mi = 0; mi < 4; ++mi)
            #pragma unroll
            for (int ni = 0; ni < 4; ++ni)
                asm volatile("v_mfma_f32_16x16x32_bf16 %0, %1, %2, %0"
                             : "+v"(acc[mi][ni]) : "v"(b[ni]), "v"(a[mi]));
        __builtin_amdgcn_s_setprio(0);
    }

    asm volatile("s_nop 7");
    asm volatile("s_nop 7");

    // ---- LDS-roundtrip epilogue ----
    __syncthreads();                                // staging dead; reuse smem
    char* ct = (char*)smem;                         // [128][128] bf16, swizzled
    #pragma unroll
    for (int mi = 0; mi < 4; ++mi) {
        int rl = wr * 64 + mi * 16 + r;             // local row
        #pragma unroll
        for (int ni = 0; ni < 4; ++ni) {
            int cl = wc * 64 + ni * 16 + g * 4;     // local col
            int gc = n0 + cl;                       // global col (EPI4 select)
            ushort4 o;
            #pragma unroll
            for (int j = 0; j < 4; ++j) {
                float v = acc[mi][ni][j];
                if (EPI == 3)      v = (v > 0.f) ? v : 0.f;
                else if (EPI == 4) v = (gc < 512) ? ((v > 0.f) ? (v + 1.f) : __expf(v))
                                                  : v * escale;
                (&o.x)[j] = f2bf(v);
            }
            int byte = (rl * 256 + cl * 2) ^ ((rl & 7) << 4);
            *(ushort4*)(ct + byte) = o;
        }
    }
    __syncthreads();
    {
        const int rr = tid >> 4, ck = tid & 15;     // 16 rows x 16 chunks/iter
        u16* slab = C; int coff = n0;
        if (EPI == 4) {
            slab = (n0 < 256) ? C : (n0 < 512) ? C + SLAB_E : C + 2 * SLAB_E;
            coff = n0 & 255;
        }
        #pragma unroll
        for (int it = 0; it < 8; ++it) {
            int rl = it * 16 + rr;
            int byte = (rl * 256 + ck * 16) ^ ((rl & 7) << 4);
            uint4 val = *(const uint4*)(ct + byte);
            size_t row = (size_t)(m0 + rl);
            if (EPI == 4)
                *(uint4*)(slab + row * 256 + coff + ck * 8) = val;
            else
                *(uint4*)(C + row * (size_t)ldc + coff + ck * 8) = val;
        }
    }
}

// ---------------------------------------------------------------------------
// gemm_ln: 128x256-tile GEMM + fused LayerNorm epilogue, LDS-roundtrip
// coalesced stores, hoisted staging. EPI: 5=LN->bf16 C; 6=LN+xres->f32 outf.
// ---------------------------------------------------------------------------
template<int EPI>
__global__ __launch_bounds__(256)
void gemm_ln(const u16* __restrict__ A1, const u16* __restrict__ A2,
             int KA, int sA1, int sA2,
             const u16* __restrict__ Bt, int ldb, int bstride,
             u16* __restrict__ C, int ldc, int K, float escale, int nx,
             const float* __restrict__ gw, const float* __restrict__ bw,
             const float* __restrict__ xres, float* __restrict__ outf)
{
    __shared__ __align__(16) u16 smem[24576];       // 48 KB: As(2x8KB), Bs(2x16KB)
    __shared__ float red[4][2][128];                // 4 KB (LN reduce)

    const int tid = threadIdx.x;
    const int nwg = gridDim.x;
    const int cpx = nwg >> 3;
    const int hb  = blockIdx.x;
    const int lb  = (hb & 7) * cpx + (hb >> 3);
    const int m0 = (lb / nx) * 128;
    const int n0 = (lb % nx) * 256;
    const int wc = tid >> 6;
    const int lane = tid & 63;
    const int g = lane >> 4, r = lane & 15;

    const u16* Btb = Bt + (size_t)(m0 / L_SEQ) * bstride;

    // hoisted staging addresses
    const u16 *pA1[2], *pA2[2], *pB[4];
    int loffA[2], loffB[4];
    #pragma unroll
    for (int i = 0; i < 2; ++i) {
        int li  = i * 256 + tid;
        int row = li >> 2, kc = li & 3;
        int kcg = kc ^ ((row >> 1) & 3);
        pA1[i] = A1 + (size_t)(m0 + row) * sA1 + kcg * 8;
        pA2[i] = A2 + (size_t)(m0 + row) * sA2 + kcg * 8 - KA;
        loffA[i] = li * 8;
    }
    #pragma unroll
    for (int i = 0; i < 4; ++i) {
        int li  = i * 256 + tid;
        int row = li >> 2, kc = li & 3;
        int kcg = kc ^ ((row >> 1) & 3);
        pB[i] = Btb + (size_t)(n0 + row) * ldb + kcg * 8;
        loffB[i] = li * 8;
    }

    f32x4 acc[8][4] = {};

    auto stage = [&](int kt, int buf) {
        u16* As_ = smem + buf * 4096;
        u16* Bs_ = smem + 8192 + buf * 8192;
        const int ko = kt * 32;
        #pragma unroll
        for (int i = 0; i < 2; ++i) {
            const u16* Ap = ((ko < KA) ? pA1[i] : pA2[i]) + ko;
            gl_lds16(Ap, &As_[loffA[i]]);
        }
        #pragma unroll
        for (int i = 0; i < 4; ++i)
            gl_lds16(pB[i] + ko, &Bs_[loffB[i]]);
    };

    const int kts = K / 32;
    const int gsw = g ^ ((r >> 1) & 3);
    stage(0, 0);
    for (int kt = 0; kt < kts; ++kt) {
        const int cur = kt & 1;
        asm volatile("s_barrier" ::: "memory");
        if (kt + 1 < kts) {
            stage(kt + 1, cur ^ 1);
            asm volatile("s_waitcnt vmcnt(6)" ::: "memory");
        } else {
            asm volatile("s_waitcnt vmcnt(0)" ::: "memory");
        }
        asm volatile("s_barrier" ::: "memory");

        const u16* Ar = smem + cur * 4096;
        const u16* Br = smem + 8192 + cur * 8192;
        s16x8 b[4];
        #pragma unroll
        for (int ni = 0; ni < 4; ++ni)
            b[ni] = *(const s16x8*)&Br[(wc * 64 + ni * 16 + r) * 32 + gsw * 8];
        __builtin_amdgcn_s_setprio(1);
        #pragma unroll
        for (int mi = 0; mi < 8; ++mi) {
            s16x8 av = *(const s16x8*)&Ar[(mi * 16 + r) * 32 + gsw * 8];
            #pragma unroll
            for (int ni = 0; ni < 4; ++ni)
                asm volatile("v_mfma_f32_16x16x32_bf16 %0, %1, %2, %0"
                             : "+v"(acc[mi][ni]) : "v"(b[ni]), "v"(av));
        }
        __builtin_amdgcn_s_setprio(0);
    }

    asm volatile("s_nop 7");
    asm volatile("s_nop 7");

    // ---- LN stats (full rows in-block) ----
    #pragma unroll
    for (int mi = 0; mi < 8; ++mi) {
        float s = 0.f, s2 = 0.f;
        #pragma unroll
        for (int ni = 0; ni < 4; ++ni)
            #pragma unroll
            for (int j = 0; j < 4; ++j) {
                float v = acc[mi][ni][j];
                s += v; s2 += v * v;
            }
        s  += __shfl_xor(s, 16);  s  += __shfl_xor(s, 32);
        s2 += __shfl_xor(s2, 16); s2 += __shfl_xor(s2, 32);
        if (g == 0) {
            red[wc][0][mi * 16 + r] = s;
            red[wc][1][mi * 16 + r] = s2;
        }
    }
    __syncthreads();

    float4 gv[4], bv[4];
    #pragma unroll
    for (int ni = 0; ni < 4; ++ni) {
        int c = wc * 64 + ni * 16 + g * 4;
        gv[ni] = *(const float4*)&gw[c];
        bv[ni] = *(const float4*)&bw[c];
    }

    char* ct = (char*)smem;
    if (EPI == 5) {
        // two halves of 64 rows (32 KB bf16 each)
        #pragma unroll
        for (int h = 0; h < 2; ++h) {
            __syncthreads();
            #pragma unroll
            for (int mi2 = 0; mi2 < 4; ++mi2) {
                int mi = h * 4 + mi2;
                int rlg = mi * 16 + r;              // row in tile
                int rl = rlg - h * 64;              // row in half
                float S  = red[0][0][rlg] + red[1][0][rlg] + red[2][0][rlg] + red[3][0][rlg];
                float S2 = red[0][1][rlg] + red[1][1][rlg] + red[2][1][rlg] + red[3][1][rlg];
                float mu = S * (1.0f / 256.0f);
                float var = S2 * (1.0f / 256.0f) - mu * mu;
                float rstd = rsqrtf(var + 1e-5f);
                #pragma unroll
                for (int ni = 0; ni < 4; ++ni) {
                    int cl = wc * 64 + ni * 16 + g * 4;
                    ushort4 o;
                    o.x = f2bf((acc[mi][ni][0] - mu) * rstd * gv[ni].x + bv[ni].x);
                    o.y = f2bf((acc[mi][ni][1] - mu) * rstd * gv[ni].y + bv[ni].y);
                    o.z = f2bf((acc[mi][ni][2] - mu) * rstd * gv[ni].z + bv[ni].z);
                    o.w = f2bf((acc[mi][ni][3] - mu) * rstd * gv[ni].w + bv[ni].w);
                    int byte = (rl * 512 + cl * 2) ^ ((rl & 7) << 4);
                    *(ushort4*)(ct + byte) = o;
                }
            }
            __syncthreads();
            const int rr = tid >> 5, ck = tid & 31; // 8 rows x 32 chunks/iter
            #pragma unroll
            for (int it = 0; it < 8; ++it) {
                int rl = it * 8 + rr;
                int byte = (rl * 512 + ck * 16) ^ ((rl & 7) << 4);
                uint4 val = *(const uint4*)(ct + byte);
                size_t row = (size_t)(m0 + h * 64 + rl);
                *(uint4*)(C + row * 256 + ck * 8) = val;
            }
        }
    } else {
        // EPI 6: four quarters of 32 rows (32 KB f32 each)
        #pragma unroll
        for (int qd = 0; qd < 4; ++qd) {
            __syncthreads();
            #pragma unroll
            for (int mi2 = 0; mi2 < 2; ++mi2) {
                int mi = qd * 2 + mi2;
                int rlg = mi * 16 + r;
                int rl = rlg - qd * 32;
                float S  = red[0][0][rlg] + red[1][0][rlg] + red[2][0][rlg] + red[3][0][rlg];
                float S2 = red[0][1][rlg] + red[1][1][rlg] + red[2][1][rlg] + red[3][1][rlg];
                float mu = S * (1.0f / 256.0f);
                float var = S2 * (1.0f / 256.0f) - mu * mu;
                float rstd = rsqrtf(var + 1e-5f);
                #pragma unroll
                for (int ni = 0; ni < 4; ++ni) {
                    int cl = wc * 64 + ni * 16 + g * 4;
                    float4 o;
                    o.x = (acc[mi][ni][0] - mu) * rstd * gv[ni].x + bv[ni].x;
                    o.y = (acc[mi][ni][1] - mu) * rstd * gv[ni].y + bv[ni].y;
                    o.z = (acc[mi][ni][2] - mu) * rstd * gv[ni].z + bv[ni].z;
                    o.w = (acc[mi][ni][3] - mu) * rstd * gv[ni].w + bv[ni].w;
                    int byte = (rl * 1024 + cl * 4) ^ ((rl & 7) << 4);
                    *(float4*)(ct + byte) = o;
                }
            }
            __syncthreads();
            const int rr = tid >> 6, ck = tid & 63; // 4 rows x 64 chunks/iter
            #pragma unroll
            for (int it = 0; it < 8; ++it) {
                int rl = it * 4 + rr;
                int byte = (rl * 1024 + ck * 16) ^ ((rl & 7) << 4);
                float4 val = *(const float4*)(ct + byte);
                size_t row = (size_t)(m0 + qd * 32 + rl);
                float4 xv = *(const float4*)&xres[row * 256 + ck * 4];
                val.x += xv.x; val.y += xv.y; val.z += xv.z; val.w += xv.w;
                *(float4*)&outf[row * 256 + ck * 4] = val;
            }
        }
    }
}

// ---------------------------------------------------------------------------
// KV partial over L-chunks: KV[32][32] += K^T v ; Ksum[32] += K. f32 accum.
// ---------------------------------------------------------------------------
__global__ __launch_bounds__(256)
void kv_partial(const u16* __restrict__ Kf, const u16* __restrict__ Vf, int ld,
                float* __restrict__ part)
{
    int b  = blockIdx.x;
    int s  = b & (KV_SPLIT - 1);
    int nh = b / KV_SPLIT;
    int h  = nh & (N_HEAD - 1);
    int n  = nh / N_HEAD;
    int t  = threadIdx.x;

    __shared__ __align__(16) float Ks[32][D_H];
    __shared__ __align__(16) float Vs[32][D_H];

    const int d   = t >> 3;
    const int dv0 = (t & 7) * 4;
    const int lr  = t >> 3;
    const int lc  = (t & 7) * 4;
    const size_t base = ((size_t)n * L_SEQ) * ld + h * D_H;

    float a0 = 0, a1 = 0, a2 = 0, a3 = 0, asum = 0;
    const int CH = L_SEQ / KV_SPLIT;
    for (int l = s * CH; l < s * CH + CH; l += 32) {
        __syncthreads();
        uint2 ku = *(const uint2*)&Kf[base + (size_t)(l + lr) * ld + lc];
        uint2 vu = *(const uint2*)&Vf[base + (size_t)(l + lr) * ld + lc];
        Ks[lr][lc] = bf2f(ku.x & 0xffff); Ks[lr][lc + 1] = bf2f(ku.x >> 16);
        Ks[lr][lc + 2] = bf2f(ku.y & 0xffff); Ks[lr][lc + 3] = bf2f(ku.y >> 16);
        Vs[lr][lc] = bf2f(vu.x & 0xffff); Vs[lr][lc + 1] = bf2f(vu.x >> 16);
        Vs[lr][lc + 2] = bf2f(vu.y & 0xffff); Vs[lr][lc + 3] = bf2f(vu.y >> 16);
        __syncthreads();
        #pragma unroll
        for (int i = 0; i < 32; ++i) {
            float kv = Ks[i][d];
            float4 vv = *(const float4*)&Vs[i][dv0];
            a0 = fmaf(kv, vv.x, a0);
            a1 = fmaf(kv, vv.y, a1);
            a2 = fmaf(kv, vv.z, a2);
            a3 = fmaf(kv, vv.w, a3);
            asum += kv;
        }
    }
    float* p = part + (size_t)b * 1056;
    p[d * D_H + dv0 + 0] = a0;
    p[d * D_H + dv0 + 1] = a1;
    p[d * D_H + dv0 + 2] = a2;
    p[d * D_H + dv0 + 3] = a3;
    if ((t & 7) == 0) p[1024 + d] = asum;
}

// ---------------------------------------------------------------------------
// kv_final + bdr build fused: per (n,h) block reduces the partials, writes
// Ksum, and emits its 32 rows of the block-diagonal bdr (values + zeros).
// bdr row (h*32+rr), col j within head block = KVs[rr][j].
// ---------------------------------------------------------------------------
__global__ __launch_bounds__(256)
void kv_final(const float* __restrict__ part, float* __restrict__ Ksum,
              u16* __restrict__ bdr)
{
    __shared__ float KVs[D_H][D_H];   // [d][dv]
    int nh = blockIdx.x;              // n*8 + h
    int h  = nh & (N_HEAD - 1);
    int n  = nh / N_HEAD;
    int t  = threadIdx.x;

    float ax = 0, ay = 0, az = 0, aw = 0, ssum = 0;
    const float* p0 = part + (size_t)nh * KV_SPLIT * 1056;
    for (int s = 0; s < KV_SPLIT; ++s) {
        const float* p = p0 + (size_t)s * 1056;
        float4 v = *(const float4*)&p[t * 4];
        ax += v.x; ay += v.y; az += v.z; aw += v.w;
        if (t < D_H) ssum += p[1024 + t];
    }
    const int d = t >> 3, dv0 = (t & 7) * 4;
    KVs[d][dv0] = ax; KVs[d][dv0 + 1] = ay; KVs[d][dv0 + 2] = az; KVs[d][dv0 + 3] = aw;
    if (t < D_H) Ksum[nh * D_H + t] = ssum;
    __syncthreads();

    const int rr = t >> 3;            // row within head block
    const int c0 = (t & 7) * 32;      // col group
    u16* dst = bdr + ((size_t)n * 256 + h * 32 + rr) * 256 + c0;
    if (c0 == h * 32) {
        #pragma unroll
        for (int j = 0; j < 32; j += 4) {
            float4 vv = *(const float4*)&KVs[rr][j];
            ushort4 o;
            o.x = f2bf(vv.x); o.y = f2bf(vv.y); o.z = f2bf(vv.z); o.w = f2bf(vv.w);
            *(ushort4*)(dst + j) = o;
        }
    } else {
        uint4 z = make_uint4(0, 0, 0, 0);
        #pragma unroll
        for (int j = 0; j < 32; j += 8)
            *(uint4*)(dst + j) = z;
    }
}

// ---------------------------------------------------------------------------
// attn_z: q[tok][c] *= L / (q[tok] . Ksum_head(c) + eps), in place.
// ---------------------------------------------------------------------------
#define NT_TOK 32
__global__ __launch_bounds__(256)
void attn_z(u16* __restrict__ q, const float* __restrict__ Ksum)
{
    const int t = threadIdx.x;
    const int w = t >> 6, lane = t & 63;
    const int tok0 = blockIdx.x * NT_TOK;
    const int n = tok0 / L_SEQ;
    float4 ks = *(const float4*)&Ksum[n * C_DIM + lane * 4];

    for (int i = 0; i < NT_TOK; i += 4) {
        int tok = tok0 + i + w;
        u16* qp = q + (size_t)tok * C_DIM + lane * 4;
        uint2 qu = *(const uint2*)qp;
        float q0 = bf2f(qu.x & 0xffff), q1 = bf2f(qu.x >> 16);
        float q2 = bf2f(qu.y & 0xffff), q3 = bf2f(qu.y >> 16);
        float p = q0 * ks.x + q1 * ks.y + q2 * ks.z + q3 * ks.w;
        p += __shfl_xor(p, 1);
        p += __shfl_xor(p, 2);
        p += __shfl_xor(p, 4);
        float z = (float)L_SEQ / (p + 1e-6f);
        uint2 o;
        o.x = (u32)f2bf(q0 * z) | ((u32)f2bf(q1 * z) << 16);
        o.y = (u32)f2bf(q2 * z) | ((u32)f2bf(q3 * z) << 16);
        *(uint2*)qp = o;
    }
}

// ---------------------------------------------------------------------------
extern "C" void kernel_launch(void* const* d_in, const int* in_sizes, int n_in,
                              void* d_out, int out_size, void* d_ws, size_t ws_size,
                              hipStream_t stream)
{
    const float* x  = (const float*)d_in[0];
    const float* Wq = (const float*)d_in[1];
    const float* Wk = (const float*)d_in[2];
    const float* Wv = (const float*)d_in[3];
    const float* Wm = (const float*)d_in[4];
    const float* W1 = (const float*)d_in[5];
    const float* W2 = (const float*)d_in[6];
    const float* g1 = (const float*)d_in[7];
    const float* b1 = (const float*)d_in[8];
    const float* g2 = (const float*)d_in[9];
    const float* b2 = (const float*)d_in[10];
    float* out = (float*)d_out;

    u16* xb  = (u16*)d_ws;          // slab 0
    u16* q   = xb + SLAB_E;         // slab 1  (q' after attn_z; h-lo after)
    u16* k   = q + SLAB_E;          // slab 2  (dead after kv -> h-hi)
    u16* v   = k + SLAB_E;          // slab 3  (dead after kv)
    u16* ln1 = v + SLAB_E;          // slab 4
    u16* h   = q;                   // spans q..k (M x 512), q'/k dead by then
    // weights (transposed bf16) + small buffers
    u16* wqkvt = ln1 + SLAB_E;             // 768*256
    u16* wmt   = wqkvt + 768 * 256;        // 256*256
    u16* w1t   = wmt + 256 * 256;          // 512*512
    u16* w2t   = w1t + 512 * 512;          // 256*512
    u16* bdr   = w2t + 256 * 512;          // 4*256*256
    u16* bdwt  = bdr + (size_t)N_BATCH * 256 * 256;   // 4*256*256, [c][b*256+k]
    float* Ksum = (float*)(bdwt + (size_t)N_BATCH * 256 * 256);
    float* part = Ksum + (size_t)N_BATCH * N_HEAD * D_H;

    dim3 blk(256);
    const float invL = 1.0f / (float)L_SEQ;

    // ---- prep (convert + all weight transposes, one launch) ----
    prep_all<<<2688, blk, 0, stream>>>(x, xb, (int)(SLAB_E / 8),
                                       Wq, Wk, Wv, Wm, W1, W2,
                                       wqkvt, wmt, w1t, w2t);

    // ---- fused QKV projection -> dense q,k,v slabs (128x128 tiles, nx=6) ----
    gemm128<4><<<(M_ROWS / 128) * 6, blk, 0, stream>>>(
        xb, xb, 256, 256, 256, wqkvt, 256, 0, q, 256, 256, invL, 6);

    // ---- KV reduction (+ fused bdr build) ----
    kv_partial<<<N_BATCH * N_HEAD * KV_SPLIT, blk, 0, stream>>>(k, v, 256, part);
    kv_final<<<N_BATCH * N_HEAD, blk, 0, stream>>>(part, Ksum, bdr);

    // ---- BDW = BD @ Wm (tiny GEMM), bdwt[c][b*256+k] ----
    gemm128<0><<<16, blk, 0, stream>>>(
        wmt, wmt, 256, 256, 256, bdr, 256, 0, bdwt, 1024, 256, 1.f, 8);

    // ---- q' = q * z (in place) ----
    attn_z<<<M_ROWS / NT_TOK, blk, 0, stream>>>(q, Ksum);

    // ---- ln1 = LN(q' @ BDW_b; g1,b1)  (fused epilogue) ----
    gemm_ln<5><<<M_ROWS / 128, blk, 0, stream>>>(
        q, q, 256, 256, 256, bdwt, 1024, 256, ln1, 256, 256, 1.f, 1,
        g1, b1, nullptr, nullptr);

    // ---- h = relu(concat(xb, ln1) @ W1)  (128x128 tiles, nx=4) ----
    gemm128<3><<<(M_ROWS / 128) * 4, blk, 0, stream>>>(
        xb, ln1, 256, 256, 256, w1t, 512, 0, h, 512, 512, 1.f, 4);

    // ---- out = x + LN(h @ W2; g2,b2)  (fused epilogue, f32 out) ----
    gemm_ln<6><<<M_ROWS / 128, blk, 0, stream>>>(
        h, h, 512, 512, 512, w2t, 512, 0, nullptr, 256, 512, 1.f, 1,
        g2, b2, x, out);
}